// Round 9
// baseline (226.657 us; speedup 1.0000x reference)
//
#include <hip/hip_runtime.h>
#include <hip/hip_fp8.h>

#define B_ 32
#define S_ 512
#define E_ 1024
#define P_ 256
#define HH 8
// rows = B*S = 16384

typedef __attribute__((ext_vector_type(8))) short bf16x8;
typedef __attribute__((ext_vector_type(8))) unsigned short us8;
typedef __attribute__((ext_vector_type(4))) unsigned short us4;
typedef __attribute__((ext_vector_type(16))) float f32x16;
typedef __attribute__((ext_vector_type(4))) float f32x4;
typedef __attribute__((ext_vector_type(8))) unsigned char u8x8;

#define SA 8.0f
#define SB 16.0f
#define SINV (1.0f / 128.0f)
#define LOG2E 1.44269504088896f
#define SINV2 (SINV * LOG2E)

static __device__ __forceinline__ unsigned short f2bf(float f) {
  union { float f; unsigned int u; } v;
  v.f = f;
  unsigned int r = (v.u + 0x7FFFu + ((v.u >> 16) & 1u)) >> 16;
  return (unsigned short)r;
}
static __device__ __forceinline__ float bf2f(unsigned short u) {
  union { unsigned int u; float f; } v;
  v.u = ((unsigned int)u) << 16;
  return v.f;
}
static __device__ __forceinline__ unsigned char f2fp8(float f) {
  return (unsigned char)__hip_cvt_float_to_fp8(f, __HIP_SATFINITE, __HIP_E4M3);
}
// HW packed fp32->bf16 RNE (2 elems / instr). No builtin on gfx950 (m240) ->
// inline asm. Same RNE rounding as f2bf, so output is bit-identical.
static __device__ __forceinline__ unsigned cvt_pk_bf16(float a, float b) {
  unsigned r;
  asm("v_cvt_pk_bf16_f32 %0, %1, %2" : "=v"(r) : "v"(a), "v"(b));
  return r;
}

// ---------------- merged prep: zero + pwB + wtB + awB8, range-dispatched ---------
// blocks: [0,160) zero 40960 floats (Z+wB+repA); [160,288) pwB; [288,384) wtB; [384,896) awB8
__global__ __launch_bounds__(256) void k_prep(const float* __restrict__ pw,
                                              const float* __restrict__ cw,
                                              const float* __restrict__ aw,
                                              unsigned short* __restrict__ pwB,
                                              unsigned short* __restrict__ wtB,
                                              unsigned char* __restrict__ awB8,
                                              float* __restrict__ zbase) {
  int bid = blockIdx.x;
  int t = threadIdx.x;
  if (bid < 160) {  // zero Z + wB + repA (contiguous)
    zbase[bid * 256 + t] = 0.f;
    return;
  }
  bid -= 160;
  if (bid < 128) {  // pw [k][n] -> pwB 32x32-frag bf16 (8 g x 16 kc-quads)
    int g = bid >> 4, kc = (bid & 15) * 4 + (t >> 6);
    int l = t & 63;
    int n = g * 32 + (l & 31);
    int kbase = kc * 16 + (l >> 5) * 8;
    us8 v;
#pragma unroll
    for (int j = 0; j < 8; j++) v[j] = f2bf(pw[(size_t)(kbase + j) * P_ + n]);
    *(us8*)(pwB + ((size_t)g * 64 + kc) * 512 + l * 8) = v;
    return;
  }
  bid -= 128;
  if (bid < 96) {  // conv_w (O,I,K) -> wtB 32x32-frag bf16 (8 g x 12 kidx-quads)
    int g = bid / 12, kidx = (bid % 12) * 4 + (t >> 6);
    int l = t & 63;
    int o = g * 32 + (l & 31);
    int xb = kidx * 16 + (l >> 5) * 8;
    us8 v;
#pragma unroll
    for (int j = 0; j < 8; j++) {
      int x = xb + j;
      int k = x >> 8, i = x & 255;
      v[j] = f2bf(cw[(size_t)o * 768 + i * 3 + k]);
    }
    *(us8*)(wtB + ((size_t)g * 48 + kidx) * 512 + l * 8) = v;
    return;
  }
  bid -= 96;
  {  // attn_w [k][j] -> awB8 16x16x32-frag fp8 x SB (256 g x 2 ks-quads)
    int g = bid >> 1, ks = (bid & 1) * 4 + (t >> 6);
    int l = t & 63;
    int j0 = g * 16 + (l & 15);
    int kbase = ks * 32 + (l >> 4) * 8;
    u8x8 v;
#pragma unroll
    for (int j = 0; j < 8; j++) v[j] = f2fp8(aw[(size_t)(kbase + j) * 4096 + j0] * SB);
    *(u8x8*)(awB8 + ((size_t)g * 8 + ks) * 512 + l * 8) = v;
  }
}

// ---------------- prep D: rep16 bf16 -> repF8 16x16x32-frag fp8 (xSA) ------------
__global__ __launch_bounds__(256) void k_swz8(const unsigned short* __restrict__ src,
                                              unsigned char* __restrict__ dst) {
  int g = blockIdx.x, ks = blockIdx.y * 4 + (threadIdx.x >> 6);
  int l = threadIdx.x & 63;
  us8 v = *(const us8*)(src + (size_t)(g * 16 + (l & 15)) * 256 + ks * 32 + (l >> 4) * 8);
  u8x8 o;
#pragma unroll
  for (int j = 0; j < 8; j++) o[j] = f2fp8(bf2f(v[j]) * SA);
  *(u8x8*)(dst + ((size_t)g * 8 + ks) * 512 + l * 8) = o;
}

// ---------------- stage 1: proj16 = bf16(x @ pw + pb)  (16384x1024x256) ----------
// R5 structure; staging conversion now uses HW v_cvt_pk_bf16_f32 (2 elems/instr)
// instead of the 4-op integer f2bf per element — m80-class kernels are VALU-
// bound on staging (VALUBusy 86%), and this cuts staging VALU ~4x. Bit-identical
// RNE rounding.
__global__ __launch_bounds__(512) void k_proj_mfma(const float* __restrict__ x,
                                                   const unsigned short* __restrict__ pwB,
                                                   const float* __restrict__ pb,
                                                   unsigned short* __restrict__ proj16) {
  __shared__ unsigned short As[16 * 64 * 8];  // (kk2*64 + row)*8, 16 KiB
  const int m0 = blockIdx.x * 64;
  const int t = threadIdx.x;
  const int w = t >> 6, lane = t & 63, ln31 = lane & 31, kh = lane >> 5;
  const int c0 = w * 32;

  f32x16 acc0, acc1;
#pragma unroll
  for (int r = 0; r < 16; r++) { acc0[r] = 0.f; acc1[r] = 0.f; }

  const unsigned short* bp = pwB + (size_t)w * 64 * 512 + lane * 8;

  for (int kc = 0; kc < E_; kc += 128) {
#pragma unroll
    for (int i = 0; i < 4; i++) {
      int c = t + i * 512;
      int row = c >> 5, pos = c & 31;
      float4 v = *(const float4*)(x + (size_t)(m0 + row) * E_ + kc + pos * 4);
      uint2 h;
      h.x = cvt_pk_bf16(v.x, v.y);
      h.y = cvt_pk_bf16(v.z, v.w);
      *(uint2*)&As[((pos >> 1) * 64 + row) * 8 + (pos & 1) * 4] = h;
    }
    __syncthreads();
    const int kcs = kc >> 4;
#pragma unroll
    for (int kk = 0; kk < 8; kk++) {
      bf16x8 a0 = *(const bf16x8*)&As[((2 * kk + kh) * 64 + ln31) * 8];
      bf16x8 a1 = *(const bf16x8*)&As[((2 * kk + kh) * 64 + 32 + ln31) * 8];
      bf16x8 b  = *(const bf16x8*)(bp + (size_t)(kcs + kk) * 512);
      acc0 = __builtin_amdgcn_mfma_f32_32x32x16_bf16(a0, b, acc0, 0, 0, 0);
      acc1 = __builtin_amdgcn_mfma_f32_32x32x16_bf16(a1, b, acc1, 0, 0, 0);
    }
    __syncthreads();
  }
  float pbv = pb[c0 + ln31];
#pragma unroll
  for (int r = 0; r < 16; r++) {
    int rl = (r & 3) + 8 * (r >> 2) + 4 * kh;
    proj16[(size_t)(m0 + rl) * P_ + c0 + ln31]      = f2bf(acc0[r] + pbv);
    proj16[(size_t)(m0 + 32 + rl) * P_ + c0 + ln31] = f2bf(acc1[r] + pbv);
  }
}

// ---------------- stage 2: conv-as-3-shift-GEMM -> rep16 (16384x768x256) ---------
// (exact R5 form)
__global__ __launch_bounds__(512) void k_conv_mfma(const unsigned short* __restrict__ proj16,
                                                   const unsigned short* __restrict__ wtB,
                                                   const float* __restrict__ cb,
                                                   const int* __restrict__ seq,
                                                   unsigned short* __restrict__ rep16) {
  __shared__ unsigned short As[32 * 66 * 8];  // (kk2*66 + row)*8, 33 KiB
  const int m0 = blockIdx.x * 64;
  const int bb = m0 >> 9, s0 = m0 & 511;
  const int t = threadIdx.x;
  const int w = t >> 6, lane = t & 63, ln31 = lane & 31, kh = lane >> 5;
  const int c0 = w * 32;

#pragma unroll
  for (int i = 0; i < 5; i++) {
    int c = t + i * 512;
    if (c < 2112) {
      int row = c >> 5, kk2 = c & 31;
      us8 v = {0, 0, 0, 0, 0, 0, 0, 0};
      if (s0 + row <= 511)
        v = *(const us8*)(proj16 + (size_t)(bb * S_ + s0 + row) * P_ + kk2 * 8);
      *(us8*)&As[(kk2 * 66 + row) * 8] = v;
    }
  }
  __syncthreads();

  f32x16 acc0, acc1;
#pragma unroll
  for (int r = 0; r < 16; r++) { acc0[r] = 0.f; acc1[r] = 0.f; }

  const unsigned short* bbase = wtB + (size_t)w * 48 * 512 + lane * 8;

#pragma unroll
  for (int k = 0; k < 3; k++) {
#pragma unroll
    for (int kk = 0; kk < 16; kk++) {
      bf16x8 a0 = *(const bf16x8*)&As[((2 * kk + kh) * 66 + k + ln31) * 8];
      bf16x8 a1 = *(const bf16x8*)&As[((2 * kk + kh) * 66 + k + 32 + ln31) * 8];
      bf16x8 b  = *(const bf16x8*)(bbase + (size_t)(k * 16 + kk) * 512);
      acc0 = __builtin_amdgcn_mfma_f32_32x32x16_bf16(a0, b, acc0, 0, 0, 0);
      acc1 = __builtin_amdgcn_mfma_f32_32x32x16_bf16(a1, b, acc1, 0, 0, 0);
    }
  }

  int l = seq[bb];
  float cbv = cb[c0 + ln31];
#pragma unroll
  for (int r = 0; r < 16; r++) {
    int rl = (r & 3) + 8 * (r >> 2) + 4 * kh;
    int s_a = s0 + rl, s_b = s0 + 32 + rl;
    float ma = (s_a >= 1 && s_a <= 509 && s_a < l - 1) ? 1.f : 0.f;
    float mb = (s_b >= 1 && s_b <= 509 && s_b < l - 1) ? 1.f : 0.f;
    rep16[(size_t)(m0 + rl) * P_ + c0 + ln31]      = f2bf(fmaxf(acc0[r] + cbv, 0.f) * ma);
    rep16[(size_t)(m0 + 32 + rl) * P_ + c0 + ln31] = f2bf(fmaxf(acc1[r] + cbv, 0.f) * mb);
  }
}

// ---------------- stage 3: fp8 16x16x32 MFMA logits + exp + h-fold + Z -> E16 ----
// EXACT R5 form — best of 6 structures tried (R0 reg-A 42us, R4 qt-split 96us,
// R5 LDS-A 40.3us, R6 qt+LDS 49.5, R7 LDS-B-pipe 46.5, R8 half-tile 49.2).
// Occupancy is NOT the lever above ~20% (R0 22%@42 vs R8 41%@49); the floor is
// the within-wave MFMA(17us)+exp(13us) dependency structure. ILP-8 acc chains +
// 2 MFMAs per A ds_read + B direct from L2 is the converged local optimum.
__global__ __launch_bounds__(256) void k_attn_mfma(const unsigned char* __restrict__ repF8,
                                                   const unsigned char* __restrict__ awB8,
                                                   const float* __restrict__ ab,
                                                   unsigned short* __restrict__ E16,
                                                   float* __restrict__ Z) {
  __shared__ __align__(16) unsigned char As8[16384];  // (rt*8+ks)*512 + lane*8
  const int m0 = blockIdx.x * 64;
  const int q0 = blockIdx.y * 128;
  const int t = threadIdx.x;
  const int w = t >> 6, lane = t & 63;
  const int ln15 = lane & 15, l4 = lane >> 4;

  // stage A frags (16 KiB for this 64-row tile): 256 thr x 4 x 16 B
  {
    const float4* src = (const float4*)(repF8 + (size_t)m0 * 256);
    float4* dst = (float4*)As8;
#pragma unroll
    for (int i = 0; i < 4; i++) dst[t + i * 256] = src[t + i * 256];
  }
  __syncthreads();

  const int qg = (q0 >> 5) + w;  // q-group 0..15 (32 q each)

  f32x4 ef[8];
#pragma unroll
  for (int i = 0; i < 8; i++) ef[i] = (f32x4){0.f, 0.f, 0.f, 0.f};

#pragma unroll 1
  for (int h = 0; h < HH; h++) {
    unsigned oz = 0;
    asm volatile("" : "+v"(oz));  // opaque 0: block LICM/CSE of A ds_reads across h
    const unsigned char* bh = awB8 + (size_t)(h * 32 + qg * 2) * 8 * 512 + lane * 8;
    f32x4 acc[8];
#pragma unroll
    for (int i = 0; i < 8; i++) acc[i] = (f32x4){0.f, 0.f, 0.f, 0.f};
#pragma unroll
    for (int ks = 0; ks < 8; ks++) {
      long b0 = *(const long*)(bh + (size_t)ks * 512);
      long b1 = *(const long*)(bh + (size_t)(8 + ks) * 512);
#pragma unroll
      for (int rt = 0; rt < 4; rt++) {
        long a = *(const long*)&As8[(rt * 8 + ks) * 512 + lane * 8 + oz];
        acc[rt * 2 + 0] = __builtin_amdgcn_mfma_f32_16x16x32_fp8_fp8(a, b0, acc[rt * 2 + 0], 0, 0, 0);
        acc[rt * 2 + 1] = __builtin_amdgcn_mfma_f32_16x16x32_fp8_fp8(a, b1, acc[rt * 2 + 1], 0, 0, 0);
      }
    }
    // ln2 folded into scale+bias: e^(x*SINV+ab) == 2^(x*SINV2 + ab*LOG2E)
    float bias0 = ab[h * 512 + qg * 32 + ln15] * LOG2E;
    float bias1 = ab[h * 512 + qg * 32 + 16 + ln15] * LOG2E;
#pragma unroll
    for (int rt = 0; rt < 4; rt++)
#pragma unroll
      for (int r = 0; r < 4; r++) {
        ef[rt * 2 + 0][r] += __builtin_amdgcn_exp2f(acc[rt * 2 + 0][r] * SINV2 + bias0);
        ef[rt * 2 + 1][r] += __builtin_amdgcn_exp2f(acc[rt * 2 + 1][r] * SINV2 + bias1);
      }
  }

#pragma unroll
  for (int rt = 0; rt < 4; rt++)
#pragma unroll
    for (int r = 0; r < 4; r++) {
      int row = m0 + rt * 16 + l4 * 4 + r;
      E16[(size_t)row * 512 + qg * 32 + ln15]      = f2bf(ef[rt * 2 + 0][r]);
      E16[(size_t)row * 512 + qg * 32 + 16 + ln15] = f2bf(ef[rt * 2 + 1][r]);
    }

#pragma unroll
  for (int rt = 0; rt < 4; rt++)
#pragma unroll
    for (int r = 0; r < 4; r++) {
      float z = ef[rt * 2 + 0][r] + ef[rt * 2 + 1][r];
#pragma unroll
      for (int st = 8; st >= 1; st >>= 1) z += __shfl_xor(z, st, 64);
      if (ln15 == 0) atomicAdd(&Z[m0 + rt * 16 + l4 * 4 + r], z);
    }
}

// ---------------- stage 4: w[b,q] = (1/H) sum_s E16[b,s,q]/Z[b,s] ----------------
__global__ __launch_bounds__(512) void k_w(const unsigned short* __restrict__ E16,
                                           const float* __restrict__ Z,
                                           float* __restrict__ wB) {
  __shared__ float rZ[64];
  int b = blockIdx.x, c = blockIdx.y, t = threadIdx.x;
  int s0 = c * 64;
  if (t < 64) rZ[t] = 1.0f / Z[b * 512 + s0 + t];
  __syncthreads();
  float acc = 0.f;
#pragma unroll 8
  for (int s = 0; s < 64; s++)
    acc += bf2f(E16[(size_t)(b * 512 + s0 + s) * 512 + t]) * rZ[s];
  atomicAdd(&wB[b * 512 + t], acc * (1.0f / HH));
}

// ---------------- stage 5a: repA[b,p] = sum_q w[b,q] * rep16[b,q,p] --------------
__global__ __launch_bounds__(256) void k_final_a(const unsigned short* __restrict__ rep16,
                                                 const float* __restrict__ wB,
                                                 float* __restrict__ repA) {
  __shared__ float wS[64];
  int b = blockIdx.x, qc = blockIdx.y, t = threadIdx.x;
  if (t < 64) wS[t] = wB[b * 512 + qc * 64 + t];
  __syncthreads();
  int p0 = (t & 63) * 4, qo = t >> 6;
  float a0 = 0.f, a1 = 0.f, a2 = 0.f, a3 = 0.f;
  for (int q = qo; q < 64; q += 4) {
    us4 v = *(const us4*)(rep16 + (size_t)(b * 512 + qc * 64 + q) * 256 + p0);
    float wq = wS[q];
    a0 += wq * bf2f(v[0]); a1 += wq * bf2f(v[1]);
    a2 += wq * bf2f(v[2]); a3 += wq * bf2f(v[3]);
  }
  atomicAdd(&repA[b * 256 + p0 + 0], a0);
  atomicAdd(&repA[b * 256 + p0 + 1], a1);
  atomicAdd(&repA[b * 256 + p0 + 2], a2);
  atomicAdd(&repA[b * 256 + p0 + 3], a3);
}

// ---------------- stage 5b: heads -> probs + argmax ------------------------------
__global__ __launch_bounds__(128) void k_final_b(const float* __restrict__ repA,
                                                 const float* __restrict__ c1w,
                                                 const float* __restrict__ c1b,
                                                 const float* __restrict__ c2w,
                                                 const float* __restrict__ c2b,
                                                 float* __restrict__ out) {
  __shared__ float hS[128];
  __shared__ float clsS[2];
  int b = blockIdx.x, t = threadIdx.x;
  float acc = c1b[t];
  for (int p = 0; p < 256; p++) acc += repA[b * 256 + p] * c1w[p * 128 + t];
  hS[t] = acc > 0.f ? acc : 0.01f * acc;
  __syncthreads();
  if (t < 2) {
    float a2 = c2b[t];
    for (int j = 0; j < 128; j++) a2 += hS[j] * c2w[j * 2 + t];
    clsS[t] = a2;
  }
  __syncthreads();
  if (t == 0) {
    float c0 = clsS[0], c1 = clsS[1];
    float m = fmaxf(c0, c1);
    float e0 = __expf(c0 - m), e1 = __expf(c1 - m);
    float inv = 1.0f / (e0 + e1);
    float p0 = e0 * inv, p1 = e1 * inv;
    out[b * 2 + 0] = p0;
    out[b * 2 + 1] = p1;
    out[B_ * 2 + b] = (p1 > p0) ? 1.0f : 0.0f;
  }
}

extern "C" void kernel_launch(void* const* d_in, const int* in_sizes, int n_in,
                              void* d_out, int out_size, void* d_ws, size_t ws_size,
                              hipStream_t stream) {
  const float* x   = (const float*)d_in[0];
  const int*   seq = (const int*)d_in[1];
  const float* pw  = (const float*)d_in[2];
  const float* pb  = (const float*)d_in[3];
  const float* cw  = (const float*)d_in[4];
  const float* cb  = (const float*)d_in[5];
  const float* aw  = (const float*)d_in[6];
  const float* ab  = (const float*)d_in[7];
  const float* c1w = (const float*)d_in[8];
  const float* c1b = (const float*)d_in[9];
  const float* c2w = (const float*)d_in[10];
  const float* c2b = (const float*)d_in[11];
  float* out = (float*)d_out;

  char* ws = (char*)d_ws;
  // proj16 (8 MiB) aliases E16 (16 MiB): proj16 dies (k_conv) before E16 written
  unsigned short* proj16 = (unsigned short*)(ws);
  unsigned short* E16    = (unsigned short*)(ws);                     // 16 MiB @ 0
  unsigned short* rep16  = (unsigned short*)(ws + (size_t)16777216);  // 8 MiB
  unsigned char*  repF8  = (unsigned char*)(ws + (size_t)25165824);   // 4 MiB
  unsigned char*  awB8   = (unsigned char*)(ws + (size_t)29360128);   // 1 MiB
  unsigned short* pwB    = (unsigned short*)(ws + (size_t)30408704);  // 512 KiB
  unsigned short* wtB    = (unsigned short*)(ws + (size_t)30932992);  // 384 KiB
  float*          Z      = (float*)(ws + (size_t)31326208);           // 64 KiB
  float*          wB     = (float*)(ws + (size_t)31391744);           // 64 KiB
  float*          repA   = (float*)(ws + (size_t)31457280);           // 32 KiB

  k_prep<<<896, 256, 0, stream>>>(pw, cw, aw, pwB, wtB, awB8, Z);
  k_proj_mfma<<<256, 512, 0, stream>>>(x, pwB, pb, proj16);
  k_conv_mfma<<<256, 512, 0, stream>>>(proj16, wtB, cb, seq, rep16);
  k_swz8<<<dim3(1024, 2), 256, 0, stream>>>(rep16, repF8);
  k_attn_mfma<<<dim3(256, 4), 256, 0, stream>>>(repF8, awB8, ab, E16, Z);
  k_w<<<dim3(32, 8), 512, 0, stream>>>(E16, Z, wB);
  k_final_a<<<dim3(32, 8), 256, 0, stream>>>(rep16, wB, repA);
  k_final_b<<<32, 128, 0, stream>>>(repA, c1w, c1b, c2w, c2b, out);
}

// Round 10
// 226.496 us; speedup vs baseline: 1.0007x; 1.0007x over previous
//
#include <hip/hip_runtime.h>
#include <hip/hip_fp8.h>

#define B_ 32
#define S_ 512
#define E_ 1024
#define P_ 256
#define HH 8
// rows = B*S = 16384

typedef __attribute__((ext_vector_type(8))) short bf16x8;
typedef __attribute__((ext_vector_type(8))) unsigned short us8;
typedef __attribute__((ext_vector_type(4))) unsigned short us4;
typedef __attribute__((ext_vector_type(16))) float f32x16;
typedef __attribute__((ext_vector_type(4))) float f32x4;
typedef __attribute__((ext_vector_type(8))) unsigned char u8x8;

#define SA 8.0f
#define SB 16.0f
#define SINV (1.0f / 128.0f)
#define LOG2E 1.44269504088896f
#define SINV2 (SINV * LOG2E)

static __device__ __forceinline__ unsigned short f2bf(float f) {
  union { float f; unsigned int u; } v;
  v.f = f;
  unsigned int r = (v.u + 0x7FFFu + ((v.u >> 16) & 1u)) >> 16;
  return (unsigned short)r;
}
static __device__ __forceinline__ float bf2f(unsigned short u) {
  union { unsigned int u; float f; } v;
  v.u = ((unsigned int)u) << 16;
  return v.f;
}
static __device__ __forceinline__ unsigned char f2fp8(float f) {
  return (unsigned char)__hip_cvt_float_to_fp8(f, __HIP_SATFINITE, __HIP_E4M3);
}

// ---------------- merged prep: zero + pwB + wtB + awB8, range-dispatched ---------
// blocks: [0,160) zero 40960 floats (Z+wB+repA); [160,288) pwB; [288,384) wtB; [384,896) awB8
__global__ __launch_bounds__(256) void k_prep(const float* __restrict__ pw,
                                              const float* __restrict__ cw,
                                              const float* __restrict__ aw,
                                              unsigned short* __restrict__ pwB,
                                              unsigned short* __restrict__ wtB,
                                              unsigned char* __restrict__ awB8,
                                              float* __restrict__ zbase) {
  int bid = blockIdx.x;
  int t = threadIdx.x;
  if (bid < 160) {  // zero Z + wB + repA (contiguous)
    zbase[bid * 256 + t] = 0.f;
    return;
  }
  bid -= 160;
  if (bid < 128) {  // pw [k][n] -> pwB 32x32-frag bf16 (8 g x 16 kc-quads)
    int g = bid >> 4, kc = (bid & 15) * 4 + (t >> 6);
    int l = t & 63;
    int n = g * 32 + (l & 31);
    int kbase = kc * 16 + (l >> 5) * 8;
    us8 v;
#pragma unroll
    for (int j = 0; j < 8; j++) v[j] = f2bf(pw[(size_t)(kbase + j) * P_ + n]);
    *(us8*)(pwB + ((size_t)g * 64 + kc) * 512 + l * 8) = v;
    return;
  }
  bid -= 128;
  if (bid < 96) {  // conv_w (O,I,K) -> wtB 32x32-frag bf16 (8 g x 12 kidx-quads)
    int g = bid / 12, kidx = (bid % 12) * 4 + (t >> 6);
    int l = t & 63;
    int o = g * 32 + (l & 31);
    int xb = kidx * 16 + (l >> 5) * 8;
    us8 v;
#pragma unroll
    for (int j = 0; j < 8; j++) {
      int x = xb + j;
      int k = x >> 8, i = x & 255;
      v[j] = f2bf(cw[(size_t)o * 768 + i * 3 + k]);
    }
    *(us8*)(wtB + ((size_t)g * 48 + kidx) * 512 + l * 8) = v;
    return;
  }
  bid -= 96;
  {  // attn_w [k][j] -> awB8 16x16x32-frag fp8 x SB (256 g x 2 ks-quads)
    int g = bid >> 1, ks = (bid & 1) * 4 + (t >> 6);
    int l = t & 63;
    int j0 = g * 16 + (l & 15);
    int kbase = ks * 32 + (l >> 4) * 8;
    u8x8 v;
#pragma unroll
    for (int j = 0; j < 8; j++) v[j] = f2fp8(aw[(size_t)(kbase + j) * 4096 + j0] * SB);
    *(u8x8*)(awB8 + ((size_t)g * 8 + ks) * 512 + l * 8) = v;
  }
}

// ---------------- prep D: rep16 bf16 -> repF8 16x16x32-frag fp8 (xSA) ------------
__global__ __launch_bounds__(256) void k_swz8(const unsigned short* __restrict__ src,
                                              unsigned char* __restrict__ dst) {
  int g = blockIdx.x, ks = blockIdx.y * 4 + (threadIdx.x >> 6);
  int l = threadIdx.x & 63;
  us8 v = *(const us8*)(src + (size_t)(g * 16 + (l & 15)) * 256 + ks * 32 + (l >> 4) * 8);
  u8x8 o;
#pragma unroll
  for (int j = 0; j < 8; j++) o[j] = f2fp8(bf2f(v[j]) * SA);
  *(u8x8*)(dst + ((size_t)g * 8 + ks) * 512 + l * 8) = o;
}

// LDS A-tile index with XOR swizzle (shorts). Same f(q,row) at write AND read.
// R9 PMC: 1.84M SQ_LDS_BANK_CONFLICT in proj — writes were 16-way conflicted
// ((pos>>1)*1024B is bank-invariant), reads 4-way (row stride 16B). XOR bits
// [5:3] (shorts) with (q ^ row>>3): write -> 2-way (free, m136), read -> 1-way.
// Bijective; 16-B alignment preserved (XOR at byte-bits [6:4]).
static __device__ __forceinline__ int aidx(int q, int row, int half) {
  return (((q * 64 + row) * 8) + half * 4) ^ (((q ^ (row >> 3)) & 7) << 3);
}

// ---------------- stage 1: proj16 = bf16(x @ pw + pb)  (16384x1024x256) ----------
// R9 PMC (first clean look at proj): 41-45us, MfmaUtil 6.5%, VALUBusy 4%, HBM
// ~1 TB/s — latency-bound at 4x the ~11us floor. Fixes: (1) XOR-swizzled LDS
// (kills the 1.8M bank-conflict cycles), (2) double-buffer with ONE barrier per
// K-chunk: next-chunk global loads issue BEFORE the MFMAs (HBM latency hides
// under compute), cvt+write after. f2bf scalar cvt kept — R9 proved inline-asm
// cvt_pk costs ~13us here (guide T12/m240: don't hand-write cvt_pk).
__global__ __launch_bounds__(512) void k_proj_mfma(const float* __restrict__ x,
                                                   const unsigned short* __restrict__ pwB,
                                                   const float* __restrict__ pb,
                                                   unsigned short* __restrict__ proj16) {
  __shared__ unsigned short As[2][16 * 64 * 8];  // 2 x 16 KiB, swizzled
  const int m0 = blockIdx.x * 64;
  const int t = threadIdx.x;
  const int w = t >> 6, lane = t & 63, ln31 = lane & 31, kh = lane >> 5;
  const int c0 = w * 32;
  const int rbase = t >> 5, pos = t & 31;  // thread stages rows rbase+{0,16,32,48}, cols pos*4..+3
  const int q = pos >> 1, half = pos & 1;

  f32x16 acc0, acc1;
#pragma unroll
  for (int r = 0; r < 16; r++) { acc0[r] = 0.f; acc1[r] = 0.f; }

  const unsigned short* bp = pwB + (size_t)w * 64 * 512 + lane * 8;
  const float* xbase = x + (size_t)(m0 + rbase) * E_ + pos * 4;

  float4 v0, v1, v2, v3;
  // prologue: load + write chunk 0
  v0 = *(const float4*)(xbase);
  v1 = *(const float4*)(xbase + 16 * E_);
  v2 = *(const float4*)(xbase + 32 * E_);
  v3 = *(const float4*)(xbase + 48 * E_);
  {
    us4 h;
    h[0] = f2bf(v0.x); h[1] = f2bf(v0.y); h[2] = f2bf(v0.z); h[3] = f2bf(v0.w);
    *(us4*)&As[0][aidx(q, rbase, half)] = h;
    h[0] = f2bf(v1.x); h[1] = f2bf(v1.y); h[2] = f2bf(v1.z); h[3] = f2bf(v1.w);
    *(us4*)&As[0][aidx(q, rbase + 16, half)] = h;
    h[0] = f2bf(v2.x); h[1] = f2bf(v2.y); h[2] = f2bf(v2.z); h[3] = f2bf(v2.w);
    *(us4*)&As[0][aidx(q, rbase + 32, half)] = h;
    h[0] = f2bf(v3.x); h[1] = f2bf(v3.y); h[2] = f2bf(v3.z); h[3] = f2bf(v3.w);
    *(us4*)&As[0][aidx(q, rbase + 48, half)] = h;
  }
  __syncthreads();

  for (int k8 = 0; k8 < 8; k8++) {
    const int cur = k8 & 1;
    if (k8 < 7) {  // issue next-chunk loads: latency hides under MFMAs below
      const float* xs = xbase + (k8 + 1) * 128;
      v0 = *(const float4*)(xs);
      v1 = *(const float4*)(xs + 16 * E_);
      v2 = *(const float4*)(xs + 32 * E_);
      v3 = *(const float4*)(xs + 48 * E_);
    }
#pragma unroll
    for (int kk = 0; kk < 8; kk++) {
      const int qr = 2 * kk + kh;
      bf16x8 a0 = *(const bf16x8*)&As[cur][aidx(qr, ln31, 0)];
      bf16x8 a1 = *(const bf16x8*)&As[cur][aidx(qr, 32 + ln31, 0)];
      bf16x8 b  = *(const bf16x8*)(bp + (size_t)(k8 * 8 + kk) * 512);
      acc0 = __builtin_amdgcn_mfma_f32_32x32x16_bf16(a0, b, acc0, 0, 0, 0);
      acc1 = __builtin_amdgcn_mfma_f32_32x32x16_bf16(a1, b, acc1, 0, 0, 0);
    }
    if (k8 < 7) {  // write next buffer (its readers finished before last barrier)
      const int nxt = cur ^ 1;
      us4 h;
      h[0] = f2bf(v0.x); h[1] = f2bf(v0.y); h[2] = f2bf(v0.z); h[3] = f2bf(v0.w);
      *(us4*)&As[nxt][aidx(q, rbase, half)] = h;
      h[0] = f2bf(v1.x); h[1] = f2bf(v1.y); h[2] = f2bf(v1.z); h[3] = f2bf(v1.w);
      *(us4*)&As[nxt][aidx(q, rbase + 16, half)] = h;
      h[0] = f2bf(v2.x); h[1] = f2bf(v2.y); h[2] = f2bf(v2.z); h[3] = f2bf(v2.w);
      *(us4*)&As[nxt][aidx(q, rbase + 32, half)] = h;
      h[0] = f2bf(v3.x); h[1] = f2bf(v3.y); h[2] = f2bf(v3.z); h[3] = f2bf(v3.w);
      *(us4*)&As[nxt][aidx(q, rbase + 48, half)] = h;
    }
    __syncthreads();
  }

  float pbv = pb[c0 + ln31];
#pragma unroll
  for (int r = 0; r < 16; r++) {
    int rl = (r & 3) + 8 * (r >> 2) + 4 * kh;
    proj16[(size_t)(m0 + rl) * P_ + c0 + ln31]      = f2bf(acc0[r] + pbv);
    proj16[(size_t)(m0 + 32 + rl) * P_ + c0 + ln31] = f2bf(acc1[r] + pbv);
  }
}

// ---------------- stage 2: conv-as-3-shift-GEMM -> rep16 (16384x768x256) ---------
// (exact R5 form)
__global__ __launch_bounds__(512) void k_conv_mfma(const unsigned short* __restrict__ proj16,
                                                   const unsigned short* __restrict__ wtB,
                                                   const float* __restrict__ cb,
                                                   const int* __restrict__ seq,
                                                   unsigned short* __restrict__ rep16) {
  __shared__ unsigned short As[32 * 66 * 8];  // (kk2*66 + row)*8, 33 KiB
  const int m0 = blockIdx.x * 64;
  const int bb = m0 >> 9, s0 = m0 & 511;
  const int t = threadIdx.x;
  const int w = t >> 6, lane = t & 63, ln31 = lane & 31, kh = lane >> 5;
  const int c0 = w * 32;

#pragma unroll
  for (int i = 0; i < 5; i++) {
    int c = t + i * 512;
    if (c < 2112) {
      int row = c >> 5, kk2 = c & 31;
      us8 v = {0, 0, 0, 0, 0, 0, 0, 0};
      if (s0 + row <= 511)
        v = *(const us8*)(proj16 + (size_t)(bb * S_ + s0 + row) * P_ + kk2 * 8);
      *(us8*)&As[(kk2 * 66 + row) * 8] = v;
    }
  }
  __syncthreads();

  f32x16 acc0, acc1;
#pragma unroll
  for (int r = 0; r < 16; r++) { acc0[r] = 0.f; acc1[r] = 0.f; }

  const unsigned short* bbase = wtB + (size_t)w * 48 * 512 + lane * 8;

#pragma unroll
  for (int k = 0; k < 3; k++) {
#pragma unroll
    for (int kk = 0; kk < 16; kk++) {
      bf16x8 a0 = *(const bf16x8*)&As[((2 * kk + kh) * 66 + k + ln31) * 8];
      bf16x8 a1 = *(const bf16x8*)&As[((2 * kk + kh) * 66 + k + 32 + ln31) * 8];
      bf16x8 b  = *(const bf16x8*)(bbase + (size_t)(k * 16 + kk) * 512);
      acc0 = __builtin_amdgcn_mfma_f32_32x32x16_bf16(a0, b, acc0, 0, 0, 0);
      acc1 = __builtin_amdgcn_mfma_f32_32x32x16_bf16(a1, b, acc1, 0, 0, 0);
    }
  }

  int l = seq[bb];
  float cbv = cb[c0 + ln31];
#pragma unroll
  for (int r = 0; r < 16; r++) {
    int rl = (r & 3) + 8 * (r >> 2) + 4 * kh;
    int s_a = s0 + rl, s_b = s0 + 32 + rl;
    float ma = (s_a >= 1 && s_a <= 509 && s_a < l - 1) ? 1.f : 0.f;
    float mb = (s_b >= 1 && s_b <= 509 && s_b < l - 1) ? 1.f : 0.f;
    rep16[(size_t)(m0 + rl) * P_ + c0 + ln31]      = f2bf(fmaxf(acc0[r] + cbv, 0.f) * ma);
    rep16[(size_t)(m0 + 32 + rl) * P_ + c0 + ln31] = f2bf(fmaxf(acc1[r] + cbv, 0.f) * mb);
  }
}

// ---------------- stage 3: fp8 16x16x32 MFMA logits + exp + h-fold + Z -> E16 ----
// EXACT R5 form — best of 6 structures tried; see R8 notes. Converged.
__global__ __launch_bounds__(256) void k_attn_mfma(const unsigned char* __restrict__ repF8,
                                                   const unsigned char* __restrict__ awB8,
                                                   const float* __restrict__ ab,
                                                   unsigned short* __restrict__ E16,
                                                   float* __restrict__ Z) {
  __shared__ __align__(16) unsigned char As8[16384];  // (rt*8+ks)*512 + lane*8
  const int m0 = blockIdx.x * 64;
  const int q0 = blockIdx.y * 128;
  const int t = threadIdx.x;
  const int w = t >> 6, lane = t & 63;
  const int ln15 = lane & 15, l4 = lane >> 4;

  // stage A frags (16 KiB for this 64-row tile): 256 thr x 4 x 16 B
  {
    const float4* src = (const float4*)(repF8 + (size_t)m0 * 256);
    float4* dst = (float4*)As8;
#pragma unroll
    for (int i = 0; i < 4; i++) dst[t + i * 256] = src[t + i * 256];
  }
  __syncthreads();

  const int qg = (q0 >> 5) + w;  // q-group 0..15 (32 q each)

  f32x4 ef[8];
#pragma unroll
  for (int i = 0; i < 8; i++) ef[i] = (f32x4){0.f, 0.f, 0.f, 0.f};

#pragma unroll 1
  for (int h = 0; h < HH; h++) {
    unsigned oz = 0;
    asm volatile("" : "+v"(oz));  // opaque 0: block LICM/CSE of A ds_reads across h
    const unsigned char* bh = awB8 + (size_t)(h * 32 + qg * 2) * 8 * 512 + lane * 8;
    f32x4 acc[8];
#pragma unroll
    for (int i = 0; i < 8; i++) acc[i] = (f32x4){0.f, 0.f, 0.f, 0.f};
#pragma unroll
    for (int ks = 0; ks < 8; ks++) {
      long b0 = *(const long*)(bh + (size_t)ks * 512);
      long b1 = *(const long*)(bh + (size_t)(8 + ks) * 512);
#pragma unroll
      for (int rt = 0; rt < 4; rt++) {
        long a = *(const long*)&As8[(rt * 8 + ks) * 512 + lane * 8 + oz];
        acc[rt * 2 + 0] = __builtin_amdgcn_mfma_f32_16x16x32_fp8_fp8(a, b0, acc[rt * 2 + 0], 0, 0, 0);
        acc[rt * 2 + 1] = __builtin_amdgcn_mfma_f32_16x16x32_fp8_fp8(a, b1, acc[rt * 2 + 1], 0, 0, 0);
      }
    }
    // ln2 folded into scale+bias: e^(x*SINV+ab) == 2^(x*SINV2 + ab*LOG2E)
    float bias0 = ab[h * 512 + qg * 32 + ln15] * LOG2E;
    float bias1 = ab[h * 512 + qg * 32 + 16 + ln15] * LOG2E;
#pragma unroll
    for (int rt = 0; rt < 4; rt++)
#pragma unroll
      for (int r = 0; r < 4; r++) {
        ef[rt * 2 + 0][r] += __builtin_amdgcn_exp2f(acc[rt * 2 + 0][r] * SINV2 + bias0);
        ef[rt * 2 + 1][r] += __builtin_amdgcn_exp2f(acc[rt * 2 + 1][r] * SINV2 + bias1);
      }
  }

#pragma unroll
  for (int rt = 0; rt < 4; rt++)
#pragma unroll
    for (int r = 0; r < 4; r++) {
      int row = m0 + rt * 16 + l4 * 4 + r;
      E16[(size_t)row * 512 + qg * 32 + ln15]      = f2bf(ef[rt * 2 + 0][r]);
      E16[(size_t)row * 512 + qg * 32 + 16 + ln15] = f2bf(ef[rt * 2 + 1][r]);
    }

#pragma unroll
  for (int rt = 0; rt < 4; rt++)
#pragma unroll
    for (int r = 0; r < 4; r++) {
      float z = ef[rt * 2 + 0][r] + ef[rt * 2 + 1][r];
#pragma unroll
      for (int st = 8; st >= 1; st >>= 1) z += __shfl_xor(z, st, 64);
      if (ln15 == 0) atomicAdd(&Z[m0 + rt * 16 + l4 * 4 + r], z);
    }
}

// ---------------- stage 4: w[b,q] = (1/H) sum_s E16[b,s,q]/Z[b,s] ----------------
__global__ __launch_bounds__(512) void k_w(const unsigned short* __restrict__ E16,
                                           const float* __restrict__ Z,
                                           float* __restrict__ wB) {
  __shared__ float rZ[64];
  int b = blockIdx.x, c = blockIdx.y, t = threadIdx.x;
  int s0 = c * 64;
  if (t < 64) rZ[t] = 1.0f / Z[b * 512 + s0 + t];
  __syncthreads();
  float acc = 0.f;
#pragma unroll 8
  for (int s = 0; s < 64; s++)
    acc += bf2f(E16[(size_t)(b * 512 + s0 + s) * 512 + t]) * rZ[s];
  atomicAdd(&wB[b * 512 + t], acc * (1.0f / HH));
}

// ---------------- stage 5a: repA[b,p] = sum_q w[b,q] * rep16[b,q,p] --------------
__global__ __launch_bounds__(256) void k_final_a(const unsigned short* __restrict__ rep16,
                                                 const float* __restrict__ wB,
                                                 float* __restrict__ repA) {
  __shared__ float wS[64];
  int b = blockIdx.x, qc = blockIdx.y, t = threadIdx.x;
  if (t < 64) wS[t] = wB[b * 512 + qc * 64 + t];
  __syncthreads();
  int p0 = (t & 63) * 4, qo = t >> 6;
  float a0 = 0.f, a1 = 0.f, a2 = 0.f, a3 = 0.f;
  for (int q = qo; q < 64; q += 4) {
    us4 v = *(const us4*)(rep16 + (size_t)(b * 512 + qc * 64 + q) * 256 + p0);
    float wq = wS[q];
    a0 += wq * bf2f(v[0]); a1 += wq * bf2f(v[1]);
    a2 += wq * bf2f(v[2]); a3 += wq * bf2f(v[3]);
  }
  atomicAdd(&repA[b * 256 + p0 + 0], a0);
  atomicAdd(&repA[b * 256 + p0 + 1], a1);
  atomicAdd(&repA[b * 256 + p0 + 2], a2);
  atomicAdd(&repA[b * 256 + p0 + 3], a3);
}

// ---------------- stage 5b: heads -> probs + argmax ------------------------------
__global__ __launch_bounds__(128) void k_final_b(const float* __restrict__ repA,
                                                 const float* __restrict__ c1w,
                                                 const float* __restrict__ c1b,
                                                 const float* __restrict__ c2w,
                                                 const float* __restrict__ c2b,
                                                 float* __restrict__ out) {
  __shared__ float hS[128];
  __shared__ float clsS[2];
  int b = blockIdx.x, t = threadIdx.x;
  float acc = c1b[t];
  for (int p = 0; p < 256; p++) acc += repA[b * 256 + p] * c1w[p * 128 + t];
  hS[t] = acc > 0.f ? acc : 0.01f * acc;
  __syncthreads();
  if (t < 2) {
    float a2 = c2b[t];
    for (int j = 0; j < 128; j++) a2 += hS[j] * c2w[j * 2 + t];
    clsS[t] = a2;
  }
  __syncthreads();
  if (t == 0) {
    float c0 = clsS[0], c1 = clsS[1];
    float m = fmaxf(c0, c1);
    float e0 = __expf(c0 - m), e1 = __expf(c1 - m);
    float inv = 1.0f / (e0 + e1);
    float p0 = e0 * inv, p1 = e1 * inv;
    out[b * 2 + 0] = p0;
    out[b * 2 + 1] = p1;
    out[B_ * 2 + b] = (p1 > p0) ? 1.0f : 0.0f;
  }
}

extern "C" void kernel_launch(void* const* d_in, const int* in_sizes, int n_in,
                              void* d_out, int out_size, void* d_ws, size_t ws_size,
                              hipStream_t stream) {
  const float* x   = (const float*)d_in[0];
  const int*   seq = (const int*)d_in[1];
  const float* pw  = (const float*)d_in[2];
  const float* pb  = (const float*)d_in[3];
  const float* cw  = (const float*)d_in[4];
  const float* cb  = (const float*)d_in[5];
  const float* aw  = (const float*)d_in[6];
  const float* ab  = (const float*)d_in[7];
  const float* c1w = (const float*)d_in[8];
  const float* c1b = (const float*)d_in[9];
  const float* c2w = (const float*)d_in[10];
  const float* c2b = (const float*)d_in[11];
  float* out = (float*)d_out;

  char* ws = (char*)d_ws;
  // proj16 (8 MiB) aliases E16 (16 MiB): proj16 dies (k_conv) before E16 written
  unsigned short* proj16 = (unsigned short*)(ws);
  unsigned short* E16    = (unsigned short*)(ws);                     // 16 MiB @ 0
  unsigned short* rep16  = (unsigned short*)(ws + (size_t)16777216);  // 8 MiB
  unsigned char*  repF8  = (unsigned char*)(ws + (size_t)25165824);   // 4 MiB
  unsigned char*  awB8   = (unsigned char*)(ws + (size_t)29360128);   // 1 MiB
  unsigned short* pwB    = (unsigned short*)(ws + (size_t)30408704);  // 512 KiB
  unsigned short* wtB    = (unsigned short*)(ws + (size_t)30932992);  // 384 KiB
  float*          Z      = (float*)(ws + (size_t)31326208);           // 64 KiB
  float*          wB     = (float*)(ws + (size_t)31391744);           // 64 KiB
  float*          repA   = (float*)(ws + (size_t)31457280);           // 32 KiB

  k_prep<<<896, 256, 0, stream>>>(pw, cw, aw, pwB, wtB, awB8, Z);
  k_proj_mfma<<<256, 512, 0, stream>>>(x, pwB, pb, proj16);
  k_conv_mfma<<<256, 512, 0, stream>>>(proj16, wtB, cb, seq, rep16);
  k_swz8<<<dim3(1024, 2), 256, 0, stream>>>(rep16, repF8);
  k_attn_mfma<<<dim3(256, 4), 256, 0, stream>>>(repF8, awB8, ab, E16, Z);
  k_w<<<dim3(32, 8), 512, 0, stream>>>(E16, Z, wB);
  k_final_a<<<dim3(32, 8), 256, 0, stream>>>(rep16, wB, repA);
  k_final_b<<<32, 128, 0, stream>>>(repA, c1w, c1b, c2w, c2b, out);
}

// Round 11
// 212.851 us; speedup vs baseline: 1.0649x; 1.0641x over previous
//
#include <hip/hip_runtime.h>
#include <hip/hip_fp8.h>

#define B_ 32
#define S_ 512
#define E_ 1024
#define P_ 256
#define HH 8
// rows = B*S = 16384

typedef __attribute__((ext_vector_type(8))) short bf16x8;
typedef __attribute__((ext_vector_type(8))) unsigned short us8;
typedef __attribute__((ext_vector_type(4))) unsigned short us4;
typedef __attribute__((ext_vector_type(16))) float f32x16;
typedef __attribute__((ext_vector_type(4))) float f32x4;
typedef __attribute__((ext_vector_type(8))) unsigned char u8x8;

#define SA 8.0f
#define SB 16.0f
#define SINV (1.0f / 128.0f)
#define LOG2E 1.44269504088896f
#define SINV2 (SINV * LOG2E)

static __device__ __forceinline__ unsigned short f2bf(float f) {
  union { float f; unsigned int u; } v;
  v.f = f;
  unsigned int r = (v.u + 0x7FFFu + ((v.u >> 16) & 1u)) >> 16;
  return (unsigned short)r;
}
static __device__ __forceinline__ float bf2f(unsigned short u) {
  union { unsigned int u; float f; } v;
  v.u = ((unsigned int)u) << 16;
  return v.f;
}
static __device__ __forceinline__ unsigned char f2fp8(float f) {
  return (unsigned char)__hip_cvt_float_to_fp8(f, __HIP_SATFINITE, __HIP_E4M3);
}

// ---------------- merged prep: zero + pwB + wtB + awB8, range-dispatched ---------
// blocks: [0,160) zero 40960 floats (Z+wB+repA); [160,288) pwB; [288,384) wtB; [384,896) awB8
__global__ __launch_bounds__(256) void k_prep(const float* __restrict__ pw,
                                              const float* __restrict__ cw,
                                              const float* __restrict__ aw,
                                              unsigned short* __restrict__ pwB,
                                              unsigned short* __restrict__ wtB,
                                              unsigned char* __restrict__ awB8,
                                              float* __restrict__ zbase) {
  int bid = blockIdx.x;
  int t = threadIdx.x;
  if (bid < 160) {  // zero Z + wB + repA (contiguous)
    zbase[bid * 256 + t] = 0.f;
    return;
  }
  bid -= 160;
  if (bid < 128) {  // pw [k][n] -> pwB 32x32-frag bf16 (8 g x 16 kc-quads)
    int g = bid >> 4, kc = (bid & 15) * 4 + (t >> 6);
    int l = t & 63;
    int n = g * 32 + (l & 31);
    int kbase = kc * 16 + (l >> 5) * 8;
    us8 v;
#pragma unroll
    for (int j = 0; j < 8; j++) v[j] = f2bf(pw[(size_t)(kbase + j) * P_ + n]);
    *(us8*)(pwB + ((size_t)g * 64 + kc) * 512 + l * 8) = v;
    return;
  }
  bid -= 128;
  if (bid < 96) {  // conv_w (O,I,K) -> wtB 32x32-frag bf16 (8 g x 12 kidx-quads)
    int g = bid / 12, kidx = (bid % 12) * 4 + (t >> 6);
    int l = t & 63;
    int o = g * 32 + (l & 31);
    int xb = kidx * 16 + (l >> 5) * 8;
    us8 v;
#pragma unroll
    for (int j = 0; j < 8; j++) {
      int x = xb + j;
      int k = x >> 8, i = x & 255;
      v[j] = f2bf(cw[(size_t)o * 768 + i * 3 + k]);
    }
    *(us8*)(wtB + ((size_t)g * 48 + kidx) * 512 + l * 8) = v;
    return;
  }
  bid -= 96;
  {  // attn_w [k][j] -> awB8 16x16x32-frag fp8 x SB (256 g x 2 ks-quads)
    int g = bid >> 1, ks = (bid & 1) * 4 + (t >> 6);
    int l = t & 63;
    int j0 = g * 16 + (l & 15);
    int kbase = ks * 32 + (l >> 4) * 8;
    u8x8 v;
#pragma unroll
    for (int j = 0; j < 8; j++) v[j] = f2fp8(aw[(size_t)(kbase + j) * 4096 + j0] * SB);
    *(u8x8*)(awB8 + ((size_t)g * 8 + ks) * 512 + l * 8) = v;
  }
}

// ---------------- stage 1: proj16 = bf16(x @ pw + pb)  (16384x1024x256) ----------
// EXACT R5 form. R9 (cvt_pk) and R10 (dbuf+swizzle) each cost +13us over this —
// the plain 2-barrier loop + scalar f2bf is proj's local optimum (implicit
// wave-level overlap already captures the pipelining gain; Common-mistake #5).
__global__ __launch_bounds__(512) void k_proj_mfma(const float* __restrict__ x,
                                                   const unsigned short* __restrict__ pwB,
                                                   const float* __restrict__ pb,
                                                   unsigned short* __restrict__ proj16) {
  __shared__ unsigned short As[16 * 64 * 8];  // (kk2*64 + row)*8, 16 KiB
  const int m0 = blockIdx.x * 64;
  const int t = threadIdx.x;
  const int w = t >> 6, lane = t & 63, ln31 = lane & 31, kh = lane >> 5;
  const int c0 = w * 32;

  f32x16 acc0, acc1;
#pragma unroll
  for (int r = 0; r < 16; r++) { acc0[r] = 0.f; acc1[r] = 0.f; }

  const unsigned short* bp = pwB + (size_t)w * 64 * 512 + lane * 8;

  for (int kc = 0; kc < E_; kc += 128) {
#pragma unroll
    for (int i = 0; i < 4; i++) {
      int c = t + i * 512;
      int row = c >> 5, pos = c & 31;
      float4 v = *(const float4*)(x + (size_t)(m0 + row) * E_ + kc + pos * 4);
      us4 h;
      h[0] = f2bf(v.x); h[1] = f2bf(v.y); h[2] = f2bf(v.z); h[3] = f2bf(v.w);
      *(us4*)&As[((pos >> 1) * 64 + row) * 8 + (pos & 1) * 4] = h;
    }
    __syncthreads();
    const int kcs = kc >> 4;
#pragma unroll
    for (int kk = 0; kk < 8; kk++) {
      bf16x8 a0 = *(const bf16x8*)&As[((2 * kk + kh) * 64 + ln31) * 8];
      bf16x8 a1 = *(const bf16x8*)&As[((2 * kk + kh) * 64 + 32 + ln31) * 8];
      bf16x8 b  = *(const bf16x8*)(bp + (size_t)(kcs + kk) * 512);
      acc0 = __builtin_amdgcn_mfma_f32_32x32x16_bf16(a0, b, acc0, 0, 0, 0);
      acc1 = __builtin_amdgcn_mfma_f32_32x32x16_bf16(a1, b, acc1, 0, 0, 0);
    }
    __syncthreads();
  }
  float pbv = pb[c0 + ln31];
#pragma unroll
  for (int r = 0; r < 16; r++) {
    int rl = (r & 3) + 8 * (r >> 2) + 4 * kh;
    proj16[(size_t)(m0 + rl) * P_ + c0 + ln31]      = f2bf(acc0[r] + pbv);
    proj16[(size_t)(m0 + 32 + rl) * P_ + c0 + ln31] = f2bf(acc1[r] + pbv);
  }
}

// ---------------- stage 2: conv-as-3-shift-GEMM -> rep16 (16384x768x256) ---------
// (exact R5 form)
__global__ __launch_bounds__(512) void k_conv_mfma(const unsigned short* __restrict__ proj16,
                                                   const unsigned short* __restrict__ wtB,
                                                   const float* __restrict__ cb,
                                                   const int* __restrict__ seq,
                                                   unsigned short* __restrict__ rep16) {
  __shared__ unsigned short As[32 * 66 * 8];  // (kk2*66 + row)*8, 33 KiB
  const int m0 = blockIdx.x * 64;
  const int bb = m0 >> 9, s0 = m0 & 511;
  const int t = threadIdx.x;
  const int w = t >> 6, lane = t & 63, ln31 = lane & 31, kh = lane >> 5;
  const int c0 = w * 32;

#pragma unroll
  for (int i = 0; i < 5; i++) {
    int c = t + i * 512;
    if (c < 2112) {
      int row = c >> 5, kk2 = c & 31;
      us8 v = {0, 0, 0, 0, 0, 0, 0, 0};
      if (s0 + row <= 511)
        v = *(const us8*)(proj16 + (size_t)(bb * S_ + s0 + row) * P_ + kk2 * 8);
      *(us8*)&As[(kk2 * 66 + row) * 8] = v;
    }
  }
  __syncthreads();

  f32x16 acc0, acc1;
#pragma unroll
  for (int r = 0; r < 16; r++) { acc0[r] = 0.f; acc1[r] = 0.f; }

  const unsigned short* bbase = wtB + (size_t)w * 48 * 512 + lane * 8;

#pragma unroll
  for (int k = 0; k < 3; k++) {
#pragma unroll
    for (int kk = 0; kk < 16; kk++) {
      bf16x8 a0 = *(const bf16x8*)&As[((2 * kk + kh) * 66 + k + ln31) * 8];
      bf16x8 a1 = *(const bf16x8*)&As[((2 * kk + kh) * 66 + k + 32 + ln31) * 8];
      bf16x8 b  = *(const bf16x8*)(bbase + (size_t)(k * 16 + kk) * 512);
      acc0 = __builtin_amdgcn_mfma_f32_32x32x16_bf16(a0, b, acc0, 0, 0, 0);
      acc1 = __builtin_amdgcn_mfma_f32_32x32x16_bf16(a1, b, acc1, 0, 0, 0);
    }
  }

  int l = seq[bb];
  float cbv = cb[c0 + ln31];
#pragma unroll
  for (int r = 0; r < 16; r++) {
    int rl = (r & 3) + 8 * (r >> 2) + 4 * kh;
    int s_a = s0 + rl, s_b = s0 + 32 + rl;
    float ma = (s_a >= 1 && s_a <= 509 && s_a < l - 1) ? 1.f : 0.f;
    float mb = (s_b >= 1 && s_b <= 509 && s_b < l - 1) ? 1.f : 0.f;
    rep16[(size_t)(m0 + rl) * P_ + c0 + ln31]      = f2bf(fmaxf(acc0[r] + cbv, 0.f) * ma);
    rep16[(size_t)(m0 + 32 + rl) * P_ + c0 + ln31] = f2bf(fmaxf(acc1[r] + cbv, 0.f) * mb);
  }
}

// ---------------- stage 3: fp8 16x16x32 MFMA logits + exp + h-fold + Z -> E16 ----
// R5 compute structure (converged; see R8 notes). ONE change: the A-stage reads
// rep16 DIRECTLY and converts bf16->fp8 inline, using k_swz8's exact index
// algebra with LDS as the destination. This deletes the separate k_swz8 kernel
// (launch + 8 MB read + 4 MB write). Reads are 16x64B coalesced lines per wave
// (same as swz8's src pattern); LDS writes contiguous 512B. Conversion is
// repeated per q-block (4x) — ~1us, cheaper than the swz8 dispatch.
__global__ __launch_bounds__(256) void k_attn_mfma(const unsigned short* __restrict__ rep16,
                                                   const unsigned char* __restrict__ awB8,
                                                   const float* __restrict__ ab,
                                                   unsigned short* __restrict__ E16,
                                                   float* __restrict__ Z) {
  __shared__ __align__(16) unsigned char As8[16384];  // (rt*8+ks)*512 + lane*8
  const int m0 = blockIdx.x * 64;
  const int q0 = blockIdx.y * 128;
  const int t = threadIdx.x;
  const int w = t >> 6, lane = t & 63;
  const int ln15 = lane & 15, l4 = lane >> 4;

  // stage A: rep16 tile (64 rows x 256 cols bf16) -> fp8 x SA frags in LDS
  {
    const int l = t & 63;
#pragma unroll
    for (int rt = 0; rt < 4; rt++)
#pragma unroll
      for (int i2 = 0; i2 < 2; i2++) {
        int ks = i2 * 4 + (t >> 6);
        us8 v = *(const us8*)(rep16 + (size_t)(m0 + rt * 16 + (l & 15)) * 256 + ks * 32 + (l >> 4) * 8);
        u8x8 o;
#pragma unroll
        for (int j = 0; j < 8; j++) o[j] = f2fp8(bf2f(v[j]) * SA);
        *(u8x8*)&As8[((rt * 8 + ks) * 512) + l * 8] = o;
      }
  }
  __syncthreads();

  const int qg = (q0 >> 5) + w;  // q-group 0..15 (32 q each)

  f32x4 ef[8];
#pragma unroll
  for (int i = 0; i < 8; i++) ef[i] = (f32x4){0.f, 0.f, 0.f, 0.f};

#pragma unroll 1
  for (int h = 0; h < HH; h++) {
    unsigned oz = 0;
    asm volatile("" : "+v"(oz));  // opaque 0: block LICM/CSE of A ds_reads across h
    const unsigned char* bh = awB8 + (size_t)(h * 32 + qg * 2) * 8 * 512 + lane * 8;
    f32x4 acc[8];
#pragma unroll
    for (int i = 0; i < 8; i++) acc[i] = (f32x4){0.f, 0.f, 0.f, 0.f};
#pragma unroll
    for (int ks = 0; ks < 8; ks++) {
      long b0 = *(const long*)(bh + (size_t)ks * 512);
      long b1 = *(const long*)(bh + (size_t)(8 + ks) * 512);
#pragma unroll
      for (int rt = 0; rt < 4; rt++) {
        long a = *(const long*)&As8[(rt * 8 + ks) * 512 + lane * 8 + oz];
        acc[rt * 2 + 0] = __builtin_amdgcn_mfma_f32_16x16x32_fp8_fp8(a, b0, acc[rt * 2 + 0], 0, 0, 0);
        acc[rt * 2 + 1] = __builtin_amdgcn_mfma_f32_16x16x32_fp8_fp8(a, b1, acc[rt * 2 + 1], 0, 0, 0);
      }
    }
    // ln2 folded into scale+bias: e^(x*SINV+ab) == 2^(x*SINV2 + ab*LOG2E)
    float bias0 = ab[h * 512 + qg * 32 + ln15] * LOG2E;
    float bias1 = ab[h * 512 + qg * 32 + 16 + ln15] * LOG2E;
#pragma unroll
    for (int rt = 0; rt < 4; rt++)
#pragma unroll
      for (int r = 0; r < 4; r++) {
        ef[rt * 2 + 0][r] += __builtin_amdgcn_exp2f(acc[rt * 2 + 0][r] * SINV2 + bias0);
        ef[rt * 2 + 1][r] += __builtin_amdgcn_exp2f(acc[rt * 2 + 1][r] * SINV2 + bias1);
      }
  }

#pragma unroll
  for (int rt = 0; rt < 4; rt++)
#pragma unroll
    for (int r = 0; r < 4; r++) {
      int row = m0 + rt * 16 + l4 * 4 + r;
      E16[(size_t)row * 512 + qg * 32 + ln15]      = f2bf(ef[rt * 2 + 0][r]);
      E16[(size_t)row * 512 + qg * 32 + 16 + ln15] = f2bf(ef[rt * 2 + 1][r]);
    }

#pragma unroll
  for (int rt = 0; rt < 4; rt++)
#pragma unroll
    for (int r = 0; r < 4; r++) {
      float z = ef[rt * 2 + 0][r] + ef[rt * 2 + 1][r];
#pragma unroll
      for (int st = 8; st >= 1; st >>= 1) z += __shfl_xor(z, st, 64);
      if (ln15 == 0) atomicAdd(&Z[m0 + rt * 16 + l4 * 4 + r], z);
    }
}

// ---------------- stage 4: w[b,q] = (1/H) sum_s E16[b,s,q]/Z[b,s] ----------------
__global__ __launch_bounds__(512) void k_w(const unsigned short* __restrict__ E16,
                                           const float* __restrict__ Z,
                                           float* __restrict__ wB) {
  __shared__ float rZ[64];
  int b = blockIdx.x, c = blockIdx.y, t = threadIdx.x;
  int s0 = c * 64;
  if (t < 64) rZ[t] = 1.0f / Z[b * 512 + s0 + t];
  __syncthreads();
  float acc = 0.f;
#pragma unroll 8
  for (int s = 0; s < 64; s++)
    acc += bf2f(E16[(size_t)(b * 512 + s0 + s) * 512 + t]) * rZ[s];
  atomicAdd(&wB[b * 512 + t], acc * (1.0f / HH));
}

// ---------------- stage 5a: repA[b,p] = sum_q w[b,q] * rep16[b,q,p] --------------
__global__ __launch_bounds__(256) void k_final_a(const unsigned short* __restrict__ rep16,
                                                 const float* __restrict__ wB,
                                                 float* __restrict__ repA) {
  __shared__ float wS[64];
  int b = blockIdx.x, qc = blockIdx.y, t = threadIdx.x;
  if (t < 64) wS[t] = wB[b * 512 + qc * 64 + t];
  __syncthreads();
  int p0 = (t & 63) * 4, qo = t >> 6;
  float a0 = 0.f, a1 = 0.f, a2 = 0.f, a3 = 0.f;
  for (int q = qo; q < 64; q += 4) {
    us4 v = *(const us4*)(rep16 + (size_t)(b * 512 + qc * 64 + q) * 256 + p0);
    float wq = wS[q];
    a0 += wq * bf2f(v[0]); a1 += wq * bf2f(v[1]);
    a2 += wq * bf2f(v[2]); a3 += wq * bf2f(v[3]);
  }
  atomicAdd(&repA[b * 256 + p0 + 0], a0);
  atomicAdd(&repA[b * 256 + p0 + 1], a1);
  atomicAdd(&repA[b * 256 + p0 + 2], a2);
  atomicAdd(&repA[b * 256 + p0 + 3], a3);
}

// ---------------- stage 5b: heads -> probs + argmax ------------------------------
__global__ __launch_bounds__(128) void k_final_b(const float* __restrict__ repA,
                                                 const float* __restrict__ c1w,
                                                 const float* __restrict__ c1b,
                                                 const float* __restrict__ c2w,
                                                 const float* __restrict__ c2b,
                                                 float* __restrict__ out) {
  __shared__ float hS[128];
  __shared__ float clsS[2];
  int b = blockIdx.x, t = threadIdx.x;
  float acc = c1b[t];
  for (int p = 0; p < 256; p++) acc += repA[b * 256 + p] * c1w[p * 128 + t];
  hS[t] = acc > 0.f ? acc : 0.01f * acc;
  __syncthreads();
  if (t < 2) {
    float a2 = c2b[t];
    for (int j = 0; j < 128; j++) a2 += hS[j] * c2w[j * 2 + t];
    clsS[t] = a2;
  }
  __syncthreads();
  if (t == 0) {
    float c0 = clsS[0], c1 = clsS[1];
    float m = fmaxf(c0, c1);
    float e0 = __expf(c0 - m), e1 = __expf(c1 - m);
    float inv = 1.0f / (e0 + e1);
    float p0 = e0 * inv, p1 = e1 * inv;
    out[b * 2 + 0] = p0;
    out[b * 2 + 1] = p1;
    out[B_ * 2 + b] = (p1 > p0) ? 1.0f : 0.0f;
  }
}

extern "C" void kernel_launch(void* const* d_in, const int* in_sizes, int n_in,
                              void* d_out, int out_size, void* d_ws, size_t ws_size,
                              hipStream_t stream) {
  const float* x   = (const float*)d_in[0];
  const int*   seq = (const int*)d_in[1];
  const float* pw  = (const float*)d_in[2];
  const float* pb  = (const float*)d_in[3];
  const float* cw  = (const float*)d_in[4];
  const float* cb  = (const float*)d_in[5];
  const float* aw  = (const float*)d_in[6];
  const float* ab  = (const float*)d_in[7];
  const float* c1w = (const float*)d_in[8];
  const float* c1b = (const float*)d_in[9];
  const float* c2w = (const float*)d_in[10];
  const float* c2b = (const float*)d_in[11];
  float* out = (float*)d_out;

  char* ws = (char*)d_ws;
  // proj16 (8 MiB) aliases E16 (16 MiB): proj16 dies (k_conv) before E16 written
  unsigned short* proj16 = (unsigned short*)(ws);
  unsigned short* E16    = (unsigned short*)(ws);                     // 16 MiB @ 0
  unsigned short* rep16  = (unsigned short*)(ws + (size_t)16777216);  // 8 MiB
  unsigned char*  awB8   = (unsigned char*)(ws + (size_t)29360128);   // 1 MiB
  unsigned short* pwB    = (unsigned short*)(ws + (size_t)30408704);  // 512 KiB
  unsigned short* wtB    = (unsigned short*)(ws + (size_t)30932992);  // 384 KiB
  float*          Z      = (float*)(ws + (size_t)31326208);           // 64 KiB
  float*          wB     = (float*)(ws + (size_t)31391744);           // 64 KiB
  float*          repA   = (float*)(ws + (size_t)31457280);           // 32 KiB

  k_prep<<<896, 256, 0, stream>>>(pw, cw, aw, pwB, wtB, awB8, Z);
  k_proj_mfma<<<256, 512, 0, stream>>>(x, pwB, pb, proj16);
  k_conv_mfma<<<256, 512, 0, stream>>>(proj16, wtB, cb, seq, rep16);
  k_attn_mfma<<<dim3(256, 4), 256, 0, stream>>>(rep16, awB8, ab, E16, Z);
  k_w<<<dim3(32, 8), 512, 0, stream>>>(E16, Z, wB);
  k_final_a<<<dim3(32, 8), 256, 0, stream>>>(rep16, wB, repA);
  k_final_b<<<32, 128, 0, stream>>>(repA, c1w, c1b, c2w, c2b, out);
}

// Round 13
// 207.415 us; speedup vs baseline: 1.0928x; 1.0262x over previous
//
#include <hip/hip_runtime.h>
#include <hip/hip_fp8.h>

#define B_ 32
#define S_ 512
#define E_ 1024
#define P_ 256
#define HH 8
// rows = B*S = 16384

typedef __attribute__((ext_vector_type(8))) short bf16x8;
typedef __attribute__((ext_vector_type(8))) unsigned short us8;
typedef __attribute__((ext_vector_type(4))) unsigned short us4;
typedef __attribute__((ext_vector_type(16))) float f32x16;
typedef __attribute__((ext_vector_type(4))) float f32x4;
typedef __attribute__((ext_vector_type(8))) unsigned char u8x8;

#define SA 8.0f
#define SB 16.0f
#define SINV (1.0f / 128.0f)
#define LOG2E 1.44269504088896f
#define SINV2 (SINV * LOG2E)

static __device__ __forceinline__ unsigned short f2bf(float f) {
  union { float f; unsigned int u; } v;
  v.f = f;
  unsigned int r = (v.u + 0x7FFFu + ((v.u >> 16) & 1u)) >> 16;
  return (unsigned short)r;
}
static __device__ __forceinline__ float bf2f(unsigned short u) {
  union { unsigned int u; float f; } v;
  v.u = ((unsigned int)u) << 16;
  return v.f;
}
static __device__ __forceinline__ unsigned char f2fp8(float f) {
  return (unsigned char)__hip_cvt_float_to_fp8(f, __HIP_SATFINITE, __HIP_E4M3);
}

// ---------------- merged prep: zero + pwB + wtB + awB8, range-dispatched ---------
// blocks: [0,160) zero 40960 floats (Z+wB+repA); [160,288) pwB; [288,384) wtB;
// [384,512) awB8 (tiled form: stage 32k x 256j aw tile into LDS (33 KB) with
// coalesced 128-B row reads, emit frags from LDS. Same output bytes as R11.)
__global__ __launch_bounds__(256) void k_prep(const float* __restrict__ pw,
                                              const float* __restrict__ cw,
                                              const float* __restrict__ aw,
                                              unsigned short* __restrict__ pwB,
                                              unsigned short* __restrict__ wtB,
                                              unsigned char* __restrict__ awB8,
                                              float* __restrict__ zbase) {
  __shared__ float ldsF[32 * 260];  // [32 k][256 j], +4 pad; 33.3 KB
  int bid = blockIdx.x;
  int t = threadIdx.x;
  if (bid < 160) {  // zero Z + wB + repA (contiguous)
    zbase[bid * 256 + t] = 0.f;
    return;
  }
  bid -= 160;
  if (bid < 128) {  // pw [k][n] -> pwB 32x32-frag bf16 (8 g x 16 kc-quads)
    int g = bid >> 4, kc = (bid & 15) * 4 + (t >> 6);
    int l = t & 63;
    int n = g * 32 + (l & 31);
    int kbase = kc * 16 + (l >> 5) * 8;
    us8 v;
#pragma unroll
    for (int j = 0; j < 8; j++) v[j] = f2bf(pw[(size_t)(kbase + j) * P_ + n]);
    *(us8*)(pwB + ((size_t)g * 64 + kc) * 512 + l * 8) = v;
    return;
  }
  bid -= 128;
  if (bid < 96) {  // conv_w (O,I,K) -> wtB 32x32-frag bf16 (8 g x 12 kidx-quads)
    int g = bid / 12, kidx = (bid % 12) * 4 + (t >> 6);
    int l = t & 63;
    int o = g * 32 + (l & 31);
    int xb = kidx * 16 + (l >> 5) * 8;
    us8 v;
#pragma unroll
    for (int j = 0; j < 8; j++) {
      int x = xb + j;
      int k = x >> 8, i = x & 255;
      v[j] = f2bf(cw[(size_t)o * 768 + i * 3 + k]);
    }
    *(us8*)(wtB + ((size_t)g * 48 + kidx) * 512 + l * 8) = v;
    return;
  }
  bid -= 96;
  {  // attn_w [k=256][j=4096] -> awB8 16x16x32-frag fp8 x SB, tiled via LDS
    int ks = bid >> 4;   // 0..7 : 32-k chunk
    int jc = bid & 15;   // 0..15: 256-j chunk
    // phase 1: coalesced load of aw[ks*32 .. +32][jc*256 .. +256] into LDS
    {
      int row = t >> 3, c8 = t & 7;  // 8 threads/row, each 8 float4
      const float* src = aw + (size_t)(ks * 32 + row) * 4096 + jc * 256;
#pragma unroll
      for (int i = 0; i < 8; i++) {
        float4 v = *(const float4*)(src + (c8 + i * 8) * 4);
        *(float4*)&ldsF[row * 260 + (c8 + i * 8) * 4] = v;
      }
    }
    __syncthreads();
    // phase 2: emit 16 frags (g = jc*16 + gl), element (l,j) = aw[k_local][col]
    int sub = t >> 6, l = t & 63;
    int kl = (l >> 4) * 8, cl = l & 15;
#pragma unroll
    for (int gi = 0; gi < 4; gi++) {
      int gl = sub * 4 + gi;
      u8x8 o;
#pragma unroll
      for (int j = 0; j < 8; j++)
        o[j] = f2fp8(ldsF[(kl + j) * 260 + gl * 16 + cl] * SB);
      int g = jc * 16 + gl;
      *(u8x8*)(awB8 + ((size_t)g * 8 + ks) * 512 + l * 8) = o;
    }
  }
}

// ---------------- stage 1: proj16 = bf16(x @ pw + pb)  (16384x1024x256) ----------
// EXACT R5 form. R9 (cvt_pk) and R10 (dbuf+swizzle) each cost +13us over this —
// the plain 2-barrier loop + scalar f2bf is proj's local optimum (implicit
// wave-level overlap already captures the pipelining gain; Common-mistake #5).
__global__ __launch_bounds__(512) void k_proj_mfma(const float* __restrict__ x,
                                                   const unsigned short* __restrict__ pwB,
                                                   const float* __restrict__ pb,
                                                   unsigned short* __restrict__ proj16) {
  __shared__ unsigned short As[16 * 64 * 8];  // (kk2*64 + row)*8, 16 KiB
  const int m0 = blockIdx.x * 64;
  const int t = threadIdx.x;
  const int w = t >> 6, lane = t & 63, ln31 = lane & 31, kh = lane >> 5;
  const int c0 = w * 32;

  f32x16 acc0, acc1;
#pragma unroll
  for (int r = 0; r < 16; r++) { acc0[r] = 0.f; acc1[r] = 0.f; }

  const unsigned short* bp = pwB + (size_t)w * 64 * 512 + lane * 8;

  for (int kc = 0; kc < E_; kc += 128) {
#pragma unroll
    for (int i = 0; i < 4; i++) {
      int c = t + i * 512;
      int row = c >> 5, pos = c & 31;
      float4 v = *(const float4*)(x + (size_t)(m0 + row) * E_ + kc + pos * 4);
      us4 h;
      h[0] = f2bf(v.x); h[1] = f2bf(v.y); h[2] = f2bf(v.z); h[3] = f2bf(v.w);
      *(us4*)&As[((pos >> 1) * 64 + row) * 8 + (pos & 1) * 4] = h;
    }
    __syncthreads();
    const int kcs = kc >> 4;
#pragma unroll
    for (int kk = 0; kk < 8; kk++) {
      bf16x8 a0 = *(const bf16x8*)&As[((2 * kk + kh) * 64 + ln31) * 8];
      bf16x8 a1 = *(const bf16x8*)&As[((2 * kk + kh) * 64 + 32 + ln31) * 8];
      bf16x8 b  = *(const bf16x8*)(bp + (size_t)(kcs + kk) * 512);
      acc0 = __builtin_amdgcn_mfma_f32_32x32x16_bf16(a0, b, acc0, 0, 0, 0);
      acc1 = __builtin_amdgcn_mfma_f32_32x32x16_bf16(a1, b, acc1, 0, 0, 0);
    }
    __syncthreads();
  }
  float pbv = pb[c0 + ln31];
#pragma unroll
  for (int r = 0; r < 16; r++) {
    int rl = (r & 3) + 8 * (r >> 2) + 4 * kh;
    proj16[(size_t)(m0 + rl) * P_ + c0 + ln31]      = f2bf(acc0[r] + pbv);
    proj16[(size_t)(m0 + 32 + rl) * P_ + c0 + ln31] = f2bf(acc1[r] + pbv);
  }
}

// ---------------- stage 2: conv-as-3-shift-GEMM -> rep16 (16384x768x256) ---------
// (exact R5 form)
__global__ __launch_bounds__(512) void k_conv_mfma(const unsigned short* __restrict__ proj16,
                                                   const unsigned short* __restrict__ wtB,
                                                   const float* __restrict__ cb,
                                                   const int* __restrict__ seq,
                                                   unsigned short* __restrict__ rep16) {
  __shared__ unsigned short As[32 * 66 * 8];  // (kk2*66 + row)*8, 33 KiB
  const int m0 = blockIdx.x * 64;
  const int bb = m0 >> 9, s0 = m0 & 511;
  const int t = threadIdx.x;
  const int w = t >> 6, lane = t & 63, ln31 = lane & 31, kh = lane >> 5;
  const int c0 = w * 32;

#pragma unroll
  for (int i = 0; i < 5; i++) {
    int c = t + i * 512;
    if (c < 2112) {
      int row = c >> 5, kk2 = c & 31;
      us8 v = {0, 0, 0, 0, 0, 0, 0, 0};
      if (s0 + row <= 511)
        v = *(const us8*)(proj16 + (size_t)(bb * S_ + s0 + row) * P_ + kk2 * 8);
      *(us8*)&As[(kk2 * 66 + row) * 8] = v;
    }
  }
  __syncthreads();

  f32x16 acc0, acc1;
#pragma unroll
  for (int r = 0; r < 16; r++) { acc0[r] = 0.f; acc1[r] = 0.f; }

  const unsigned short* bbase = wtB + (size_t)w * 48 * 512 + lane * 8;

#pragma unroll
  for (int k = 0; k < 3; k++) {
#pragma unroll
    for (int kk = 0; kk < 16; kk++) {
      bf16x8 a0 = *(const bf16x8*)&As[((2 * kk + kh) * 66 + k + ln31) * 8];
      bf16x8 a1 = *(const bf16x8*)&As[((2 * kk + kh) * 66 + k + 32 + ln31) * 8];
      bf16x8 b  = *(const bf16x8*)(bbase + (size_t)(k * 16 + kk) * 512);
      acc0 = __builtin_amdgcn_mfma_f32_32x32x16_bf16(a0, b, acc0, 0, 0, 0);
      acc1 = __builtin_amdgcn_mfma_f32_32x32x16_bf16(a1, b, acc1, 0, 0, 0);
    }
  }

  int l = seq[bb];
  float cbv = cb[c0 + ln31];
#pragma unroll
  for (int r = 0; r < 16; r++) {
    int rl = (r & 3) + 8 * (r >> 2) + 4 * kh;
    int s_a = s0 + rl, s_b = s0 + 32 + rl;
    float ma = (s_a >= 1 && s_a <= 509 && s_a < l - 1) ? 1.f : 0.f;
    float mb = (s_b >= 1 && s_b <= 509 && s_b < l - 1) ? 1.f : 0.f;
    rep16[(size_t)(m0 + rl) * P_ + c0 + ln31]      = f2bf(fmaxf(acc0[r] + cbv, 0.f) * ma);
    rep16[(size_t)(m0 + 32 + rl) * P_ + c0 + ln31] = f2bf(fmaxf(acc1[r] + cbv, 0.f) * mb);
  }
}

// ---------------- stage 3: fp8 16x16x32 MFMA logits + exp + h-fold + Z -> E16 ----
// (exact R11 form: R5 compute + inline bf16->fp8 A-stage from rep16; converged)
__global__ __launch_bounds__(256) void k_attn_mfma(const unsigned short* __restrict__ rep16,
                                                   const unsigned char* __restrict__ awB8,
                                                   const float* __restrict__ ab,
                                                   unsigned short* __restrict__ E16,
                                                   float* __restrict__ Z) {
  __shared__ __align__(16) unsigned char As8[16384];  // (rt*8+ks)*512 + lane*8
  const int m0 = blockIdx.x * 64;
  const int q0 = blockIdx.y * 128;
  const int t = threadIdx.x;
  const int w = t >> 6, lane = t & 63;
  const int ln15 = lane & 15, l4 = lane >> 4;

  // stage A: rep16 tile (64 rows x 256 cols bf16) -> fp8 x SA frags in LDS
  {
    const int l = t & 63;
#pragma unroll
    for (int rt = 0; rt < 4; rt++)
#pragma unroll
      for (int i2 = 0; i2 < 2; i2++) {
        int ks = i2 * 4 + (t >> 6);
        us8 v = *(const us8*)(rep16 + (size_t)(m0 + rt * 16 + (l & 15)) * 256 + ks * 32 + (l >> 4) * 8);
        u8x8 o;
#pragma unroll
        for (int j = 0; j < 8; j++) o[j] = f2fp8(bf2f(v[j]) * SA);
        *(u8x8*)&As8[((rt * 8 + ks) * 512) + l * 8] = o;
      }
  }
  __syncthreads();

  const int qg = (q0 >> 5) + w;  // q-group 0..15 (32 q each)

  f32x4 ef[8];
#pragma unroll
  for (int i = 0; i < 8; i++) ef[i] = (f32x4){0.f, 0.f, 0.f, 0.f};

#pragma unroll 1
  for (int h = 0; h < HH; h++) {
    unsigned oz = 0;
    asm volatile("" : "+v"(oz));  // opaque 0: block LICM/CSE of A ds_reads across h
    const unsigned char* bh = awB8 + (size_t)(h * 32 + qg * 2) * 8 * 512 + lane * 8;
    f32x4 acc[8];
#pragma unroll
    for (int i = 0; i < 8; i++) acc[i] = (f32x4){0.f, 0.f, 0.f, 0.f};
#pragma unroll
    for (int ks = 0; ks < 8; ks++) {
      long b0 = *(const long*)(bh + (size_t)ks * 512);
      long b1 = *(const long*)(bh + (size_t)(8 + ks) * 512);
#pragma unroll
      for (int rt = 0; rt < 4; rt++) {
        long a = *(const long*)&As8[(rt * 8 + ks) * 512 + lane * 8 + oz];
        acc[rt * 2 + 0] = __builtin_amdgcn_mfma_f32_16x16x32_fp8_fp8(a, b0, acc[rt * 2 + 0], 0, 0, 0);
        acc[rt * 2 + 1] = __builtin_amdgcn_mfma_f32_16x16x32_fp8_fp8(a, b1, acc[rt * 2 + 1], 0, 0, 0);
      }
    }
    // ln2 folded into scale+bias: e^(x*SINV+ab) == 2^(x*SINV2 + ab*LOG2E)
    float bias0 = ab[h * 512 + qg * 32 + ln15] * LOG2E;
    float bias1 = ab[h * 512 + qg * 32 + 16 + ln15] * LOG2E;
#pragma unroll
    for (int rt = 0; rt < 4; rt++)
#pragma unroll
      for (int r = 0; r < 4; r++) {
        ef[rt * 2 + 0][r] += __builtin_amdgcn_exp2f(acc[rt * 2 + 0][r] * SINV2 + bias0);
        ef[rt * 2 + 1][r] += __builtin_amdgcn_exp2f(acc[rt * 2 + 1][r] * SINV2 + bias1);
      }
  }

#pragma unroll
  for (int rt = 0; rt < 4; rt++)
#pragma unroll
    for (int r = 0; r < 4; r++) {
      int row = m0 + rt * 16 + l4 * 4 + r;
      E16[(size_t)row * 512 + qg * 32 + ln15]      = f2bf(ef[rt * 2 + 0][r]);
      E16[(size_t)row * 512 + qg * 32 + 16 + ln15] = f2bf(ef[rt * 2 + 1][r]);
    }

#pragma unroll
  for (int rt = 0; rt < 4; rt++)
#pragma unroll
    for (int r = 0; r < 4; r++) {
      float z = ef[rt * 2 + 0][r] + ef[rt * 2 + 1][r];
#pragma unroll
      for (int st = 8; st >= 1; st >>= 1) z += __shfl_xor(z, st, 64);
      if (ln15 == 0) atomicAdd(&Z[m0 + rt * 16 + l4 * 4 + r], z);
    }
}

// ---------------- stage 4: w[b,q] = (1/H) sum_s E16[b,s,q]/Z[b,s] ----------------
// Vectorized (Common-mistake #2 fix): R11 read E16 as SCALAR 2-B bf16 loads.
// Now thread (qg=t&63, sg=t>>6) loads us8 (16 B) per s, LDS-reduces over sg.
__global__ __launch_bounds__(512) void k_w(const unsigned short* __restrict__ E16,
                                           const float* __restrict__ Z,
                                           float* __restrict__ wB) {
  __shared__ float rZ[64];
  __shared__ float red[8][64][8];
  int b = blockIdx.x, c = blockIdx.y, t = threadIdx.x;
  int s0 = c * 64;
  if (t < 64) rZ[t] = 1.0f / Z[b * 512 + s0 + t];
  __syncthreads();
  int qg = t & 63, sg = t >> 6;
  float acc[8];
#pragma unroll
  for (int j = 0; j < 8; j++) acc[j] = 0.f;
#pragma unroll
  for (int i = 0; i < 8; i++) {
    int si = sg * 8 + i;
    us8 v = *(const us8*)(E16 + (size_t)(b * 512 + s0 + si) * 512 + qg * 8);
    float rz = rZ[si];
#pragma unroll
    for (int j = 0; j < 8; j++) acc[j] += bf2f(v[j]) * rz;
  }
#pragma unroll
  for (int j = 0; j < 8; j++) red[sg][qg][j] = acc[j];
  __syncthreads();
  int qg2 = t >> 3, j2 = t & 7;
  float s = 0.f;
#pragma unroll
  for (int g = 0; g < 8; g++) s += red[g][qg2][j2];
  atomicAdd(&wB[b * 512 + qg2 * 8 + j2], s * (1.0f / HH));
}

// ---------------- stage 5a: repA[b,p] = sum_q w[b,q] * rep16[b,q,p] --------------
__global__ __launch_bounds__(256) void k_final_a(const unsigned short* __restrict__ rep16,
                                                 const float* __restrict__ wB,
                                                 float* __restrict__ repA) {
  __shared__ float wS[64];
  int b = blockIdx.x, qc = blockIdx.y, t = threadIdx.x;
  if (t < 64) wS[t] = wB[b * 512 + qc * 64 + t];
  __syncthreads();
  int p0 = (t & 63) * 4, qo = t >> 6;
  float a0 = 0.f, a1 = 0.f, a2 = 0.f, a3 = 0.f;
  for (int q = qo; q < 64; q += 4) {
    us4 v = *(const us4*)(rep16 + (size_t)(b * 512 + qc * 64 + q) * 256 + p0);
    float wq = wS[q];
    a0 += wq * bf2f(v[0]); a1 += wq * bf2f(v[1]);
    a2 += wq * bf2f(v[2]); a3 += wq * bf2f(v[3]);
  }
  atomicAdd(&repA[b * 256 + p0 + 0], a0);
  atomicAdd(&repA[b * 256 + p0 + 1], a1);
  atomicAdd(&repA[b * 256 + p0 + 2], a2);
  atomicAdd(&repA[b * 256 + p0 + 3], a3);
}

// ---------------- stage 5b: heads -> probs + argmax ------------------------------
__global__ __launch_bounds__(128) void k_final_b(const float* __restrict__ repA,
                                                 const float* __restrict__ c1w,
                                                 const float* __restrict__ c1b,
                                                 const float* __restrict__ c2w,
                                                 const float* __restrict__ c2b,
                                                 float* __restrict__ out) {
  __shared__ float hS[128];
  __shared__ float clsS[2];
  int b = blockIdx.x, t = threadIdx.x;
  float acc = c1b[t];
  for (int p = 0; p < 256; p++) acc += repA[b * 256 + p] * c1w[p * 128 + t];
  hS[t] = acc > 0.f ? acc : 0.01f * acc;
  __syncthreads();
  if (t < 2) {
    float a2 = c2b[t];
    for (int j = 0; j < 128; j++) a2 += hS[j] * c2w[j * 2 + t];
    clsS[t] = a2;
  }
  __syncthreads();
  if (t == 0) {
    float c0 = clsS[0], c1 = clsS[1];
    float m = fmaxf(c0, c1);
    float e0 = __expf(c0 - m), e1 = __expf(c1 - m);
    float inv = 1.0f / (e0 + e1);
    float p0 = e0 * inv, p1 = e1 * inv;
    out[b * 2 + 0] = p0;
    out[b * 2 + 1] = p1;
    out[B_ * 2 + b] = (p1 > p0) ? 1.0f : 0.0f;
  }
}

extern "C" void kernel_launch(void* const* d_in, const int* in_sizes, int n_in,
                              void* d_out, int out_size, void* d_ws, size_t ws_size,
                              hipStream_t stream) {
  const float* x   = (const float*)d_in[0];
  const int*   seq = (const int*)d_in[1];
  const float* pw  = (const float*)d_in[2];
  const float* pb  = (const float*)d_in[3];
  const float* cw  = (const float*)d_in[4];
  const float* cb  = (const float*)d_in[5];
  const float* aw  = (const float*)d_in[6];
  const float* ab  = (const float*)d_in[7];
  const float* c1w = (const float*)d_in[8];
  const float* c1b = (const float*)d_in[9];
  const float* c2w = (const float*)d_in[10];
  const float* c2b = (const float*)d_in[11];
  float* out = (float*)d_out;

  char* ws = (char*)d_ws;
  // proj16 (8 MiB) aliases E16 (16 MiB): proj16 dies (k_conv) before E16 written
  unsigned short* proj16 = (unsigned short*)(ws);
  unsigned short* E16    = (unsigned short*)(ws);                     // 16 MiB @ 0
  unsigned short* rep16  = (unsigned short*)(ws + (size_t)16777216);  // 8 MiB
  unsigned char*  awB8   = (unsigned char*)(ws + (size_t)29360128);   // 1 MiB
  unsigned short* pwB    = (unsigned short*)(ws + (size_t)30408704);  // 512 KiB
  unsigned short* wtB    = (unsigned short*)(ws + (size_t)30932992);  // 384 KiB
  float*          Z      = (float*)(ws + (size_t)31326208);           // 64 KiB
  float*          wB     = (float*)(ws + (size_t)31391744);           // 64 KiB
  float*          repA   = (float*)(ws + (size_t)31457280);           // 32 KiB

  k_prep<<<512, 256, 0, stream>>>(pw, cw, aw, pwB, wtB, awB8, Z);
  k_proj_mfma<<<256, 512, 0, stream>>>(x, pwB, pb, proj16);
  k_conv_mfma<<<256, 512, 0, stream>>>(proj16, wtB, cb, seq, rep16);
  k_attn_mfma<<<dim3(256, 4), 256, 0, stream>>>(rep16, awB8, ab, E16, Z);
  k_w<<<dim3(32, 8), 512, 0, stream>>>(E16, Z, wB);
  k_final_a<<<dim3(32, 8), 256, 0, stream>>>(rep16, wB, repA);
  k_final_b<<<32, 128, 0, stream>>>(repA, c1w, c1b, c2w, c2b, out);
}